// Round 1
// baseline (402.385 us; speedup 1.0000x reference)
//
#include <hip/hip_runtime.h>
#include <stdint.h>

// ImpulseNoise (salt & pepper), bit-exact re-implementation of JAX threefry2x32
// under the jax_threefry_partitionable=True (modern default) code path.
//
// key(42) = (0, 42)
// split:   k_flip = TF(key, (0,0)),  k_salt = TF(key, (0,1))   [fold-like split]
// bits[i] = TF(k, (0, i)).x0 ^ TF(k, (0, i)).x1                [partitionable bits]
// u       = bitcast_f32((bits >> 9) | 0x3F800000) - 1.0f
// out     = (u_flip <= 0.09f) ? ((u_salt <= 0.5f) ? 1.0f : 0.0f) : img
//
// V2: VALU-bound (VALUBusy ~100%, HBM 21%). Two levers, both bit-exact:
//  1. Rotates forced to v_alignbit_b32 (1 op) via __builtin_amdgcn_alignbit —
//     the compiler was emitting shl+shr+or (3 ops), and a round is add+rot+xor.
//  2. Uniform-compare done in integers: uf <= T  <=>  bits < ((floor(T*2^23)+1)<<9),
//     exact because uf = m*2^-23 exactly and thresholds are constexpr-folded.

__host__ __device__ constexpr uint32_t rotl32(uint32_t x, int r) {
    return (x << r) | (x >> (32 - r));
}

struct TF2 { uint32_t a, b; };

// Host/constexpr reference threefry — used only for compile-time key derivation.
__host__ __device__ constexpr TF2 threefry2x32(uint32_t k0, uint32_t k1,
                                               uint32_t x0, uint32_t x1) {
    const uint32_t ks0 = k0;
    const uint32_t ks1 = k1;
    const uint32_t ks2 = k0 ^ k1 ^ 0x1BD11BDAu;
    x0 += ks0; x1 += ks1;
    x0 += x1; x1 = rotl32(x1, 13); x1 ^= x0;
    x0 += x1; x1 = rotl32(x1, 15); x1 ^= x0;
    x0 += x1; x1 = rotl32(x1, 26); x1 ^= x0;
    x0 += x1; x1 = rotl32(x1,  6); x1 ^= x0;
    x0 += ks1; x1 += ks2 + 1u;
    x0 += x1; x1 = rotl32(x1, 17); x1 ^= x0;
    x0 += x1; x1 = rotl32(x1, 29); x1 ^= x0;
    x0 += x1; x1 = rotl32(x1, 16); x1 ^= x0;
    x0 += x1; x1 = rotl32(x1, 24); x1 ^= x0;
    x0 += ks2; x1 += ks0 + 2u;
    x0 += x1; x1 = rotl32(x1, 13); x1 ^= x0;
    x0 += x1; x1 = rotl32(x1, 15); x1 ^= x0;
    x0 += x1; x1 = rotl32(x1, 26); x1 ^= x0;
    x0 += x1; x1 = rotl32(x1,  6); x1 ^= x0;
    x0 += ks0; x1 += ks1 + 3u;
    x0 += x1; x1 = rotl32(x1, 17); x1 ^= x0;
    x0 += x1; x1 = rotl32(x1, 29); x1 ^= x0;
    x0 += x1; x1 = rotl32(x1, 16); x1 ^= x0;
    x0 += x1; x1 = rotl32(x1, 24); x1 ^= x0;
    x0 += ks1; x1 += ks2 + 4u;
    x0 += x1; x1 = rotl32(x1, 13); x1 ^= x0;
    x0 += x1; x1 = rotl32(x1, 15); x1 ^= x0;
    x0 += x1; x1 = rotl32(x1, 26); x1 ^= x0;
    x0 += x1; x1 = rotl32(x1,  6); x1 ^= x0;
    x0 += ks2; x1 += ks0 + 5u;
    return {x0, x1};
}

// Compile-time key derivation: seed 42 -> key (0, 42); fold-like split.
constexpr uint32_t SEED_HI = 0u;
constexpr uint32_t SEED_LO = 42u;
constexpr TF2 KFLIP = threefry2x32(SEED_HI, SEED_LO, 0u, 0u);
constexpr TF2 KSALT = threefry2x32(SEED_HI, SEED_LO, 0u, 1u);

// Integer thresholds (exact):
//   uf = (bits>>9) * 2^-23 exactly.  uf <= 0.09f  <=>  (bits>>9) <= floor(0.09f*2^23)
//   (0.09f*2^23 is not an integer, so floor comparison is exact and <= vs < is safe)
//   (bits>>9) <= M  <=>  bits < (M+1)<<9
constexpr uint32_t FLIP_T = (((uint32_t)((double)0.09f * 8388608.0)) + 1u) << 9;
//   us <= 0.5f  <=>  (bits>>9) <= 0x400000  <=>  bits < 0x80000200
constexpr uint32_t SALT_T = 0x80000200u;

// Single-instruction rotate: v_alignbit_b32(x, x, 32-r) == rotl(x, r)
__device__ __forceinline__ uint32_t rotl_d(uint32_t x, int r) {
    return __builtin_amdgcn_alignbit(x, x, 32u - (uint32_t)r);
}

#define TFR(rot) { x0 += x1; x1 = rotl_d(x1, rot); x1 ^= x0; }

// Device threefry with key as template constants: all key-schedule adds fold to
// immediates; x0's initial injection folds (counter hi word is 0).
// Returns x0 ^ x1 (the partitionable-bits output word).
template <uint32_t K0, uint32_t K1>
__device__ __forceinline__ uint32_t tf_bits(uint32_t ctr) {
    constexpr uint32_t K2 = K0 ^ K1 ^ 0x1BD11BDAu;
    uint32_t x0 = K0;            // 0 + ks0
    uint32_t x1 = ctr + K1;
    TFR(13) TFR(15) TFR(26) TFR(6)
    x0 += K1; x1 += K2 + 1u;
    TFR(17) TFR(29) TFR(16) TFR(24)
    x0 += K2; x1 += K0 + 2u;
    TFR(13) TFR(15) TFR(26) TFR(6)
    x0 += K0; x1 += K1 + 3u;
    TFR(17) TFR(29) TFR(16) TFR(24)
    x0 += K1; x1 += K2 + 4u;
    TFR(13) TFR(15) TFR(26) TFR(6)
    x0 += K2; x1 += K0 + 5u;
    return x0 ^ x1;
}

__global__ __launch_bounds__(256)
void ImpulseNoise_32040456028513_kernel(const float4* __restrict__ in,
                                        float4* __restrict__ out,
                                        unsigned n4) {
    unsigned tid = blockIdx.x * blockDim.x + threadIdx.x;
    if (tid >= n4) return;

    float4 v = in[tid];
    float r[4] = {v.x, v.y, v.z, v.w};
    const uint32_t base = tid << 2;

#pragma unroll
    for (int j = 0; j < 4; ++j) {
        const uint32_t i = base + (uint32_t)j;
        // Two independent cipher chains per element; always computed (P(no lane
        // in a wave flips) ~ e^-24, so lane-skipping saves nothing).
        uint32_t bits_f = tf_bits<KFLIP.a, KFLIP.b>(i);
        uint32_t bits_s = tf_bits<KSALT.a, KSALT.b>(i);
        float sp = (bits_s < SALT_T) ? 1.0f : 0.0f;
        r[j] = (bits_f < FLIP_T) ? sp : r[j];
    }

    out[tid] = make_float4(r[0], r[1], r[2], r[3]);
}

extern "C" void kernel_launch(void* const* d_in, const int* in_sizes, int n_in,
                              void* d_out, int out_size, void* d_ws, size_t ws_size,
                              hipStream_t stream) {
    const float4* in = (const float4*)d_in[0];
    float4* out = (float4*)d_out;
    unsigned n = (unsigned)in_sizes[0];   // 64*3*512*512 = 50331648, divisible by 4
    unsigned n4 = n >> 2;
    unsigned blocks = (n4 + 255u) / 256u;
    ImpulseNoise_32040456028513_kernel<<<blocks, 256, 0, stream>>>(in, out, n4);
}